// Round 3
// baseline (429.519 us; speedup 1.0000x reference)
//
#include <hip/hip_runtime.h>
#include <hip/hip_bf16.h>
#include <math.h>

#define K_ 4
#define B_ 64
#define S_ 50
#define D_ 256
#define V_ 40000
#define H_ 4
#define DH_ 64
#define NEG_ (-1e9f)
#define SCALE_ 0.125f

typedef __attribute__((ext_vector_type(8))) __bf16 bf16x8v;
typedef __attribute__((ext_vector_type(4))) float f32x4v;

// ---------- helpers ----------
__device__ __forceinline__ float wred_sum(float v) {
#pragma unroll
  for (int off = 32; off > 0; off >>= 1) v += __shfl_xor(v, off, 64);
  return v;
}
__device__ __forceinline__ float wred_max(float v) {
#pragma unroll
  for (int off = 32; off > 0; off >>= 1) v = fmaxf(v, __shfl_xor(v, off, 64));
  return v;
}
__device__ __forceinline__ float softplusf(float x) {
  return (x > 20.f) ? x : log1pf(expf(x));
}
__device__ __forceinline__ float geluf(float x) {
  const float c = 0.7978845608028654f;  // sqrt(2/pi)
  float x3 = x * x * x;
  return 0.5f * x * (1.f + tanhf(c * (x + 0.044715f * x3)));
}
__device__ __forceinline__ float bf2f(unsigned int u) {
  return __uint_as_float(u << 16);
}
__device__ __forceinline__ unsigned short f2bf(float f) {
  unsigned u = __float_as_uint(f);
  return (unsigned short)((u + 0x7fffu + ((u >> 16) & 1u)) >> 16);
}
__device__ __forceinline__ void unp8(uint4 a, float* d) {
  d[0] = bf2f(a.x & 0xffffu); d[1] = bf2f(a.x >> 16);
  d[2] = bf2f(a.y & 0xffffu); d[3] = bf2f(a.y >> 16);
  d[4] = bf2f(a.z & 0xffffu); d[5] = bf2f(a.z >> 16);
  d[6] = bf2f(a.w & 0xffffu); d[7] = bf2f(a.w >> 16);
}
__device__ __forceinline__ bf16x8v cvt8(float4 a, float4 b) {
  bf16x8v r;
  r[0] = (__bf16)a.x; r[1] = (__bf16)a.y; r[2] = (__bf16)a.z; r[3] = (__bf16)a.w;
  r[4] = (__bf16)b.x; r[5] = (__bf16)b.y; r[6] = (__bf16)b.z; r[7] = (__bf16)b.w;
  return r;
}

// ---------- fused front: local_agg+gather+LN1 [0,256) | weight cast [256,1024)
// | gating [1024,1824). All three mutually independent.
// Shared-mem regions carved from one block (62816 B):
//   hgb  [64][264] bf16  @ 0      (33792)
//   e_f  [50][68]  f32   @ 33792  (13600)
//   adj  [64][64]  u8    @ 47392  (4096)
//   a_sb [4][264]  bf16  @ 51488  (2112)
//   alp  [64][72]  bf16  @ 53600  (9216)
//   hl   [50][260] f32   @ 0      (52000)  -- overlays hgb..a_sb AFTER PV
__global__ __launch_bounds__(256) void front_kernel(
    const int* __restrict__ items, const int* __restrict__ adj,
    const float* __restrict__ emb, const float* __restrict__ agg_a,
    const int* __restrict__ alias_, float* __restrict__ hbuf,
    unsigned short* __restrict__ xb,
    const float* __restrict__ ln1g, const float* __restrict__ ln1b,
    const int* __restrict__ ids, const float* __restrict__ Wg,
    const float* __restrict__ Wn, const float* __restrict__ eps,
    float* __restrict__ gates,
    const float* __restrict__ wq, const float* __restrict__ wk,
    const float* __restrict__ wv, const float* __restrict__ wo,
    const float* __restrict__ w1, const float* __restrict__ w2,
    unsigned short* __restrict__ wqkvT, unsigned short* __restrict__ woT,
    unsigned short* __restrict__ w1T, unsigned short* __restrict__ w2T) {
  __shared__ __align__(16) char smem[62816];
  int bid = blockIdx.x;
  int t = threadIdx.x;

  if (bid < 256) {
    // ======== local aggregator (MFMA) + alias gather + LN1 ========
    typedef __bf16 (*arr264)[264];
    arr264 hgb = (arr264)smem;
    float (*e_f)[68] = (float(*)[68])(smem + 33792);
    unsigned char (*adj_s)[64] = (unsigned char(*)[64])(smem + 47392);
    arr264 a_sb = (arr264)(smem + 51488);
    __bf16 (*alp)[72] = (__bf16(*)[72])(smem + 53600);
    float* hl = (float*)smem;  // [50][260] overlay, used after PV

    int kb = bid;
    int k = kb >> 6, b = kb & 63;
    for (int c = t; c < 2048; c += 256) {
      int row = c >> 5, c8 = (c & 31) * 8;
      bf16x8v val;
      if (row < S_) {
        int g = items[kb * S_ + row];
        const float* src = emb + ((long)k * V_ + g) * D_ + c8;
        val = cvt8(*(const float4*)src, *(const float4*)(src + 4));
      } else {
#pragma unroll
        for (int e = 0; e < 8; ++e) val[e] = (__bf16)0.f;
      }
      *(bf16x8v*)&hgb[row][c8] = val;
    }
    if (t < 128) {
      int row = t >> 5, c8 = (t & 31) * 8;
      const float* src = agg_a + ((long)k * 4 + row) * D_ + c8;
      *(bf16x8v*)&a_sb[row][c8] = cvt8(*(const float4*)src, *(const float4*)(src + 4));
    }
    for (int c = t; c < 4096; c += 256) {
      int i = c >> 6, j = c & 63;
      adj_s[i][j] = (i < S_ && j < S_)
                        ? (unsigned char)adj[((long)b * S_ + i) * S_ + j] : 0;
    }
    __syncthreads();
    int w = t >> 6, lane = t & 63;
    int m16 = lane & 15, quad = lane >> 4;
    float e_sel[4][4];
#pragma unroll
    for (int nt = 0; nt < 4; ++nt)
#pragma unroll
      for (int rg = 0; rg < 4; ++rg) e_sel[nt][rg] = NEG_;
#pragma unroll
    for (int r = 0; r < 4; ++r) {
      f32x4v acc[4];
#pragma unroll
      for (int nt = 0; nt < 4; ++nt) acc[nt] = (f32x4v){0.f, 0.f, 0.f, 0.f};
#pragma unroll
      for (int k0 = 0; k0 < 8; ++k0) {
        int kc = k0 * 32 + quad * 8;
        bf16x8v hr = *(const bf16x8v*)&hgb[w * 16 + m16][kc];
        bf16x8v ar = *(const bf16x8v*)&a_sb[r][kc];
        bf16x8v af;
#pragma unroll
        for (int e = 0; e < 8; ++e) af[e] = (__bf16)((float)hr[e] * (float)ar[e]);
#pragma unroll
        for (int nt = 0; nt < 4; ++nt) {
          bf16x8v bf = *(const bf16x8v*)&hgb[nt * 16 + m16][kc];
          acc[nt] = __builtin_amdgcn_mfma_f32_16x16x32_bf16(af, bf, acc[nt], 0, 0, 0);
        }
      }
#pragma unroll
      for (int nt = 0; nt < 4; ++nt)
#pragma unroll
        for (int rg = 0; rg < 4; ++rg) {
          int i = w * 16 + quad * 4 + rg, j = nt * 16 + m16;
          if (adj_s[i][j] == r + 1) {
            float v = acc[nt][rg];
            e_sel[nt][rg] = (v >= 0.f) ? v : 0.2f * v;
          }
        }
    }
#pragma unroll
    for (int nt = 0; nt < 4; ++nt)
#pragma unroll
      for (int rg = 0; rg < 4; ++rg) {
        int i = w * 16 + quad * 4 + rg;
        if (i < S_) e_f[i][nt * 16 + m16] = e_sel[nt][rg];
      }
    __syncthreads();
    for (int i = w; i < S_; i += 4) {
      float val = (lane < S_) ? e_f[i][lane] : -INFINITY;
      float m = wred_max(val);
      float p = expf(val - m);
      float ssum = wred_sum(p);
      alp[i][lane] = (__bf16)(p / ssum);
    }
    __syncthreads();
    // PV with register-buffered accumulators (hgb/alp stay live)
    f32x4v acc16[16];
#pragma unroll
    for (int nt = 0; nt < 16; ++nt) {
      f32x4v acc = (f32x4v){0.f, 0.f, 0.f, 0.f};
#pragma unroll
      for (int k0 = 0; k0 < 2; ++k0) {
        int jb = k0 * 32 + quad * 8;
        bf16x8v af = *(const bf16x8v*)&alp[w * 16 + m16][jb];
        bf16x8v bf;
#pragma unroll
        for (int tt = 0; tt < 8; ++tt) bf[tt] = hgb[jb + tt][nt * 16 + m16];
        acc = __builtin_amdgcn_mfma_f32_16x16x32_bf16(af, bf, acc, 0, 0, 0);
      }
      acc16[nt] = acc;
    }
    __syncthreads();  // all hgb/alp reads done; overlay hl on smem
#pragma unroll
    for (int nt = 0; nt < 16; ++nt)
#pragma unroll
      for (int rg = 0; rg < 4; ++rg) {
        int i = w * 16 + quad * 4 + rg;
        if (i < S_) hl[i * 260 + nt * 16 + m16] = acc16[nt][rg];
      }
    __syncthreads();
    // alias gather + LN1 from LDS -> hbuf fp32 + xb bf16
    for (int s = w; s < S_; s += 4) {
      int src = alias_[b * S_ + s];
      const float4 v = *(const float4*)&hl[src * 260 + lane * 4];
      long off = ((long)kb * S_ + s) * D_ + lane * 4;
      *(float4*)(hbuf + off) = v;
      float sum = wred_sum(v.x + v.y + v.z + v.w);
      float sq = wred_sum(v.x * v.x + v.y * v.y + v.z * v.z + v.w * v.w);
      float mean = sum * (1.f / D_);
      float var = sq * (1.f / D_) - mean * mean;
      float rs = rsqrtf(var + 1e-5f);
      const float4 gv = *(const float4*)(ln1g + k * D_ + lane * 4);
      const float4 bv = *(const float4*)(ln1b + k * D_ + lane * 4);
      ushort4 o;
      o.x = f2bf((v.x - mean) * rs * gv.x + bv.x);
      o.y = f2bf((v.y - mean) * rs * gv.y + bv.y);
      o.z = f2bf((v.z - mean) * rs * gv.z + bv.z);
      o.w = f2bf((v.w - mean) * rs * gv.w + bv.w);
      *(ushort4*)(xb + off) = o;
    }
    return;
  }

  if (bid < 1024) {
    // ======== weight cast: LDS-tiled 64x64 transpose, coalesced both sides ====
    int tid = bid - 256;
    typedef unsigned short row66[66];
    row66* tile = (row66*)smem;  // needs 8448 B
    const float* src; unsigned short* dst; int C, R; int r0, c0;
    if (tid < 192) {  // Wq|Wk|Wv [256][256] per k -> wqkvT rows sect*256+
      int sect = tid >> 6; int rem = tid & 63;
      int k = rem >> 4, t2 = rem & 15;
      r0 = (t2 >> 2) * 64; c0 = (t2 & 3) * 64;
      src = ((sect == 0) ? wq : (sect == 1) ? wk : wv) + (long)k * 65536;
      dst = wqkvT + ((long)k * 768 + sect * 256) * 256;
      R = 256; C = 256;
    } else if (tid < 256) {  // Wo
      int rem = tid - 192; int k = rem >> 4, t2 = rem & 15;
      r0 = (t2 >> 2) * 64; c0 = (t2 & 3) * 64;
      src = wo + (long)k * 65536; dst = woT + (long)k * 65536;
      R = 256; C = 256;
    } else if (tid < 512) {  // W1 [256][1024] -> w1T [1024][256]
      int rem = tid - 256; int k = rem >> 6, t2 = rem & 63;
      r0 = (t2 >> 4) * 64; c0 = (t2 & 15) * 64;
      src = w1 + (long)k * 262144; dst = w1T + (long)k * 262144;
      R = 256; C = 1024;
    } else {  // W2 [1024][256] -> w2T [256][1024]
      int rem = tid - 512; int k = rem >> 6, t2 = rem & 63;
      r0 = (t2 >> 2) * 64; c0 = (t2 & 3) * 64;
      src = w2 + (long)k * 262144; dst = w2T + (long)k * 262144;
      R = 1024; C = 256;
    }
    int sr = t >> 2, sc = (t & 3) * 16;
    const float* p = src + (long)(r0 + sr) * C + c0 + sc;
#pragma unroll
    for (int q = 0; q < 4; ++q) {
      float4 f = *(const float4*)(p + q * 4);
      tile[sr][sc + q * 4 + 0] = f2bf(f.x);
      tile[sr][sc + q * 4 + 1] = f2bf(f.y);
      tile[sr][sc + q * 4 + 2] = f2bf(f.z);
      tile[sr][sc + q * 4 + 3] = f2bf(f.w);
    }
    __syncthreads();
    int dc = t >> 2, ch = (t & 3) * 16;  // dst row c0+dc, cols r0+ch..+16
    unsigned int wds[8];
#pragma unroll
    for (int i = 0; i < 8; ++i)
      wds[i] = (unsigned int)tile[ch + 2 * i][dc] |
               ((unsigned int)tile[ch + 2 * i + 1][dc] << 16);
    unsigned short* dp = dst + (long)(c0 + dc) * R + r0 + ch;
    uint4 o0 = make_uint4(wds[0], wds[1], wds[2], wds[3]);
    uint4 o1 = make_uint4(wds[4], wds[5], wds[6], wds[7]);
    *(uint4*)dp = o0;
    *(uint4*)(dp + 8) = o1;
    return;
  }

  {
    // ======== noisy top-k gating ========
    int w = t >> 6, lane = t & 63;
    int item = (bid - 1024) * 4 + w;  // b*S+s
    int b = item / S_, s = item % S_;
    int d0 = lane * 4;
    float4 hs = make_float4(0.f, 0.f, 0.f, 0.f);
#pragma unroll
    for (int k = 0; k < K_; ++k) {
      int id = ids[(k * B_ + b) * S_ + s];
      const float4 e = *(const float4*)(emb + ((long)k * V_ + id) * D_ + d0);
      hs.x += e.x; hs.y += e.y; hs.z += e.z; hs.w += e.w;
    }
    hs.x *= 0.25f; hs.y *= 0.25f; hs.z *= 0.25f; hs.w *= 0.25f;
    float logit[4];
#pragma unroll
    for (int j = 0; j < K_; ++j) {
      float pg = hs.x * Wg[(d0 + 0) * K_ + j] + hs.y * Wg[(d0 + 1) * K_ + j] +
                 hs.z * Wg[(d0 + 2) * K_ + j] + hs.w * Wg[(d0 + 3) * K_ + j];
      float pn = hs.x * Wn[(d0 + 0) * K_ + j] + hs.y * Wn[(d0 + 1) * K_ + j] +
                 hs.z * Wn[(d0 + 2) * K_ + j] + hs.w * Wn[(d0 + 3) * K_ + j];
      pg = wred_sum(pg);
      pn = wred_sum(pn);
      logit[j] = pg + softplusf(pn) * eps[item * K_ + j];
    }
    if (lane == 0) {
      int i0 = 0; float v0 = logit[0];
      for (int j = 1; j < K_; ++j) if (logit[j] > v0) { v0 = logit[j]; i0 = j; }
      int i1 = -1; float v1 = 0.f;
      for (int j = 0; j < K_; ++j)
        if (j != i0 && (i1 < 0 || logit[j] > v1)) { v1 = logit[j]; i1 = j; }
      float w0 = 1.f / (1.f + expf(v1 - v0));
      float w1 = 1.f - w0;
#pragma unroll
      for (int j = 0; j < K_; ++j)
        gates[item * K_ + j] = (j == i0) ? w0 : ((j == i1) ? w1 : 0.f);
    }
  }
}

// ---------- bf16 MFMA GEMM: 128x128 tile, 4 waves (2x2), BK=64, Bt=[N][Kd].
// Grid: x = col tile (fastest, shares A panel in L2), y = row tile, z = key.
__global__ __launch_bounds__(256) void bgemm3(
    const unsigned short* __restrict__ A, const unsigned short* __restrict__ Bt,
    long strideA, long strideBt, int N, int Kd,
    unsigned short* __restrict__ Cb, long strideCb, int act) {
  __shared__ unsigned short sA[128][72];
  __shared__ unsigned short sB[128][72];
  int z = blockIdx.z;
  A += (long)z * strideA;
  Bt += (long)z * strideBt;
  int t = threadIdx.x, w = t >> 6, lane = t & 63;
  int wr = w >> 1, wc = w & 1;
  int row0 = blockIdx.y * 128, col0 = blockIdx.x * 128;
  int m16 = lane & 15, quad = lane >> 4;
  f32x4v acc[4][4];
#pragma unroll
  for (int mr = 0; mr < 4; ++mr)
#pragma unroll
    for (int nr = 0; nr < 4; ++nr) acc[mr][nr] = (f32x4v){0.f, 0.f, 0.f, 0.f};
  // staging: thread t covers row t>>1, k-cols (t&1)*32 + {0..31}
  int sr = t >> 1, sc = (t & 1) * 32;
  const unsigned short* pa = A + (long)(row0 + sr) * Kd + sc;
  const unsigned short* pb = Bt + (long)(col0 + sr) * Kd + sc;
  uint4 a0 = *(const uint4*)(pa);
  uint4 a1 = *(const uint4*)(pa + 8);
  uint4 a2 = *(const uint4*)(pa + 16);
  uint4 a3 = *(const uint4*)(pa + 24);
  uint4 b0 = *(const uint4*)(pb);
  uint4 b1 = *(const uint4*)(pb + 8);
  uint4 b2 = *(const uint4*)(pb + 16);
  uint4 b3 = *(const uint4*)(pb + 24);
  for (int k0 = 0; k0 < Kd; k0 += 64) {
    __syncthreads();
    *(uint4*)&sA[sr][sc] = a0;
    *(uint4*)&sA[sr][sc + 8] = a1;
    *(uint4*)&sA[sr][sc + 16] = a2;
    *(uint4*)&sA[sr][sc + 24] = a3;
    *(uint4*)&sB[sr][sc] = b0;
    *(uint4*)&sB[sr][sc + 8] = b1;
    *(uint4*)&sB[sr][sc + 16] = b2;
    *(uint4*)&sB[sr][sc + 24] = b3;
    if (k0 + 64 < Kd) {
      a0 = *(const uint4*)(pa + k0 + 64);
      a1 = *(const uint4*)(pa + k0 + 72);
      a2 = *(const uint4*)(pa + k0 + 80);
      a3 = *(const uint4*)(pa + k0 + 88);
      b0 = *(const uint4*)(pb + k0 + 64);
      b1 = *(const uint4*)(pb + k0 + 72);
      b2 = *(const uint4*)(pb + k0 + 80);
      b3 = *(const uint4*)(pb + k0 + 88);
    }
    __syncthreads();
#pragma unroll
    for (int half = 0; half < 2; ++half) {
      int kg = half * 32 + quad * 8;
      bf16x8v af[4], bf[4];
#pragma unroll
      for (int i = 0; i < 4; ++i) {
        af[i] = *(const bf16x8v*)&sA[wr * 64 + i * 16 + m16][kg];
        bf[i] = *(const bf16x8v*)&sB[wc * 64 + i * 16 + m16][kg];
      }
#pragma unroll
      for (int mr = 0; mr < 4; ++mr)
#pragma unroll
        for (int nr = 0; nr < 4; ++nr)
          acc[mr][nr] = __builtin_amdgcn_mfma_f32_16x16x32_bf16(
              af[mr], bf[nr], acc[mr][nr], 0, 0, 0);
    }
  }
  // epilogue: C/D layout col=lane&15, row=quad*4+reg [m89/m91]
#pragma unroll
  for (int mr = 0; mr < 4; ++mr) {
    int rbase = row0 + wr * 64 + mr * 16 + quad * 4;
#pragma unroll
    for (int nr = 0; nr < 4; ++nr) {
      int col = col0 + wc * 64 + nr * 16 + m16;
#pragma unroll
      for (int i2 = 0; i2 < 4; ++i2) {
        float vv = acc[mr][nr][i2];
        if (act == 1) vv = geluf(vv);
        Cb[(long)z * strideCb + (long)(rbase + i2) * N + col] = f2bf(vv);
      }
    }
  }
}

// ---------- causal MHA ----------
__global__ __launch_bounds__(256) void attn_kernel(
    const unsigned short* __restrict__ qkv, unsigned short* __restrict__ o) {
  __shared__ float qs[S_][65], ks[S_][65], vs[S_][65];
  int idx = blockIdx.x;
  int h = idx & 3;
  int kb = idx >> 2;
  long base = (long)kb * S_ * 768;
  int t = threadIdx.x;
  for (int f = t; f < S_ * 8; f += 256) {
    int row = f >> 3, c8 = (f & 7) * 8;
    long g = base + (long)row * 768 + h * DH_ + c8;
    unp8(*(const uint4*)(qkv + g), &qs[row][c8]);
    unp8(*(const uint4*)(qkv + g + 256), &ks[row][c8]);
    unp8(*(const uint4*)(qkv + g + 512), &vs[row][c8]);
  }
  __syncthreads();
  int w = t >> 6, lane = t & 63;
  for (int i = w; i < S_; i += 4) {
    int jj = (lane < S_) ? lane : 0;
    float dot = 0.f;
#pragma unroll
    for (int d = 0; d < DH_; ++d) dot = fmaf(qs[i][d], ks[jj][d], dot);
    float val = (lane <= i) ? dot * SCALE_ : ((lane < S_) ? NEG_ : -INFINITY);
    float m = wred_max(val);
    float p = expf(val - m);
    float ssum = wred_sum(p);
    float pr = p / ssum;
    float acc = 0.f;
    for (int j = 0; j <= i; ++j)
      acc = fmaf(__shfl(pr, j, 64), vs[j][lane], acc);
    o[((long)kb * S_ + i) * D_ + h * DH_ + lane] = f2bf(acc);
  }
}

// ---------- O-projection + residual + LN2 fused (64x256 tile, full rows) ------
__global__ __launch_bounds__(256) void bgemm_oln(
    const unsigned short* __restrict__ A, const unsigned short* __restrict__ Bt,
    float* __restrict__ hbuf, unsigned short* __restrict__ y,
    const float* __restrict__ g2, const float* __restrict__ b2) {
  __shared__ unsigned short sA[64][72];
  __shared__ unsigned short sB[256][72];
  const long BSD = (long)B_ * S_ * D_;
  int z = blockIdx.z;
  const unsigned short* Ap = A + (long)z * BSD;
  const unsigned short* Bp = Bt + (long)z * 65536;
  int t = threadIdx.x, w = t >> 6, lane = t & 63;
  int row0 = blockIdx.x * 64;
  int m16 = lane & 15, quad = lane >> 4;
  f32x4v acc[16];
#pragma unroll
  for (int nt = 0; nt < 16; ++nt) acc[nt] = (f32x4v){0.f, 0.f, 0.f, 0.f};
  int sr = t >> 2, sc = (t & 3) * 16;
  const unsigned short* pa = Ap + (long)(row0 + sr) * 256 + sc;
  const unsigned short* pb = Bp + (long)sr * 256 + sc;  // + q*64 rows = +q*16384
  uint4 a0 = *(const uint4*)pa;
  uint4 a1 = *(const uint4*)(pa + 8);
  uint4 bv[8];
#pragma unroll
  for (int q = 0; q < 4; ++q) {
    bv[2 * q] = *(const uint4*)(pb + q * 16384);
    bv[2 * q + 1] = *(const uint4*)(pb + q * 16384 + 8);
  }
  for (int k0 = 0; k0 < 256; k0 += 64) {
    __syncthreads();
    *(uint4*)&sA[sr][sc] = a0;
    *(uint4*)&sA[sr][sc + 8] = a1;
#pragma unroll
    for (int q = 0; q < 4; ++q) {
      *(uint4*)&sB[q * 64 + sr][sc] = bv[2 * q];
      *(uint4*)&sB[q * 64 + sr][sc + 8] = bv[2 * q + 1];
    }
    if (k0 + 64 < 256) {
      a0 = *(const uint4*)(pa + k0 + 64);
      a1 = *(const uint4*)(pa + k0 + 72);
#pragma unroll
      for (int q = 0; q < 4; ++q) {
        bv[2 * q] = *(const uint4*)(pb + q * 16384 + k0 + 64);
        bv[2 * q + 1] = *(const uint4*)(pb + q * 16384 + k0 + 72);
      }
    }
    __syncthreads();
#pragma unroll
    for (int half = 0; half < 2; ++half) {
      int kg = half * 32 + quad * 8;
      bf16x8v af = *(const bf16x8v*)&sA[w * 16 + m16][kg];
#pragma unroll
      for (int nt = 0; nt < 16; ++nt) {
        bf16x8v bf = *(const bf16x8v*)&sB[nt * 16 + m16][kg];
        acc[nt] = __builtin_amdgcn_mfma_f32_16x16x32_bf16(af, bf, acc[nt], 0, 0, 0);
      }
    }
  }
  // epilogue: v = gemm + h  ->  hbuf (residual); LN(v) -> y bf16
  long zoff = (long)z * BSD;
  int rbase = row0 + w * 16 + quad * 4;
#pragma unroll
  for (int nt = 0; nt < 16; ++nt)
#pragma unroll
    for (int i2 = 0; i2 < 4; ++i2) {
      long off = zoff + (long)(rbase + i2) * 256 + nt * 16 + m16;
      float vv = acc[nt][i2] + hbuf[off];
      acc[nt][i2] = vv;
      hbuf[off] = vv;
    }
  float mean[4], rstd[4];
#pragma unroll
  for (int i2 = 0; i2 < 4; ++i2) {
    float s = 0.f, q = 0.f;
#pragma unroll
    for (int nt = 0; nt < 16; ++nt) {
      float vv = acc[nt][i2];
      s += vv; q += vv * vv;
    }
#pragma unroll
    for (int off = 1; off < 16; off <<= 1) {  // reduce over m16 lanes (same quad)
      s += __shfl_xor(s, off, 64);
      q += __shfl_xor(q, off, 64);
    }
    float m = s * (1.f / D_);
    float var = q * (1.f / D_) - m * m;
    mean[i2] = m;
    rstd[i2] = rsqrtf(var + 1e-5f);
  }
#pragma unroll
  for (int nt = 0; nt < 16; ++nt) {
    float gv = g2[z * D_ + nt * 16 + m16];
    float bvv = b2[z * D_ + nt * 16 + m16];
#pragma unroll
    for (int i2 = 0; i2 < 4; ++i2) {
      long off = zoff + (long)(rbase + i2) * 256 + nt * 16 + m16;
      y[off] = f2bf((acc[nt][i2] - mean[i2]) * rstd[i2] * gv + bvv);
    }
  }
}

// ---------- FFN2 + residual + gated combine, z in grid, atomic accumulate ----
// Grid: x = col tile (4), y = row tile (50), z = key (4). out pre-zeroed.
__global__ __launch_bounds__(256) void bgemm_f2a(
    const unsigned short* __restrict__ A, const unsigned short* __restrict__ Bt,
    const float* __restrict__ hbuf, const float* __restrict__ gates,
    float* __restrict__ out) {
  __shared__ unsigned short sA[64][72];
  __shared__ unsigned short sB[64][72];
  const long T4 = 3276800;   // per-key stride of tb [3200][1024]
  const long BSD = (long)B_ * S_ * D_;
  int z = blockIdx.z;
  int t = threadIdx.x, w = t >> 6, lane = t & 63;
  int col0 = blockIdx.x * 64, row0 = blockIdx.y * 64;
  int m16 = lane & 15, quad = lane >> 4;
  f32x4v acc[4];
#pragma unroll
  for (int nt = 0; nt < 4; ++nt) acc[nt] = (f32x4v){0.f, 0.f, 0.f, 0.f};
  int sr = t >> 2, sc = (t & 3) * 16;
  const unsigned short* pa = A + (long)z * T4 + (long)(row0 + sr) * 1024 + sc;
  const unsigned short* pb = Bt + (long)z * 262144 + (long)(col0 + sr) * 1024 + sc;
  uint4 a0 = *(const uint4*)pa;
  uint4 a1 = *(const uint4*)(pa + 8);
  uint4 b0 = *(const uint4*)pb;
  uint4 b1 = *(const uint4*)(pb + 8);
  for (int k0 = 0; k0 < 1024; k0 += 64) {
    __syncthreads();
    *(uint4*)&sA[sr][sc] = a0;
    *(uint4*)&sA[sr][sc + 8] = a1;
    *(uint4*)&sB[sr][sc] = b0;
    *(uint4*)&sB[sr][sc + 8] = b1;
    if (k0 + 64 < 1024) {
      a0 = *(const uint4*)(pa + k0 + 64);
      a1 = *(const uint4*)(pa + k0 + 72);
      b0 = *(const uint4*)(pb + k0 + 64);
      b1 = *(const uint4*)(pb + k0 + 72);
    }
    __syncthreads();
#pragma unroll
    for (int half = 0; half < 2; ++half) {
      int kg = half * 32 + quad * 8;
      bf16x8v af = *(const bf16x8v*)&sA[w * 16 + m16][kg];
#pragma unroll
      for (int nt = 0; nt < 4; ++nt) {
        bf16x8v bf = *(const bf16x8v*)&sB[nt * 16 + m16][kg];
        acc[nt] = __builtin_amdgcn_mfma_f32_16x16x32_bf16(af, bf, acc[nt], 0, 0, 0);
      }
    }
  }
  // epilogue: out += g_z * (gemm + h_z); skip atomics when gate is exactly 0
  int rbase = row0 + w * 16 + quad * 4;
#pragma unroll
  for (int i2 = 0; i2 < 4; ++i2) {
    float gz = gates[(rbase + i2) * 4 + z];
    if (gz != 0.f) {
#pragma unroll
      for (int nt = 0; nt < 4; ++nt) {
        long off = (long)(rbase + i2) * 256 + col0 + nt * 16 + m16;
        float vv = gz * (acc[nt][i2] + hbuf[(long)z * BSD + off]);
        atomicAdd(&out[off], vv);
      }
    }
  }
}

extern "C" void kernel_launch(void* const* d_in, const int* in_sizes, int n_in,
                              void* d_out, int out_size, void* d_ws,
                              size_t ws_size, hipStream_t stream) {
  const int* ids = (const int*)d_in[0];
  const int* items = (const int*)d_in[1];
  const int* adj = (const int*)d_in[2];
  const int* alias = (const int*)d_in[3];
  const float* eps = (const float*)d_in[4];
  const float* emb = (const float*)d_in[5];
  const float* agg_a = (const float*)d_in[6];
  const float* Wq = (const float*)d_in[7];
  const float* Wk = (const float*)d_in[8];
  const float* Wv = (const float*)d_in[9];
  const float* Wo = (const float*)d_in[10];
  const float* ln1g = (const float*)d_in[11];
  const float* ln1b = (const float*)d_in[12];
  const float* W1 = (const float*)d_in[13];
  const float* W2 = (const float*)d_in[14];
  const float* ln2g = (const float*)d_in[15];
  const float* ln2b = (const float*)d_in[16];
  const float* Wg = (const float*)d_in[17];
  const float* Wn = (const float*)d_in[18];
  float* out = (float*)d_out;

  const long BSD = (long)B_ * S_ * D_;  // 819200
  float* ws = (float*)d_ws;
  float* gates = ws;                    // 16384 fp32
  float* hbuf = ws + 16384;             // [K,B,S,D] fp32 residual stream
  unsigned short* ub = (unsigned short*)(ws + 16384 + 4 * BSD);
  unsigned short* xb = ub;              // x / attn-o / y slot [K,B,S,D] bf16
  unsigned short* qkvb = ub + 3276800;  // [K,B*S,768]
  unsigned short* tb = qkvb;            // FFN hidden [K,B*S,1024]
  unsigned short* wqkvT = ub + 16384000;
  unsigned short* woT = wqkvT + 786432;
  unsigned short* w1T = woT + 262144;
  unsigned short* w2T = w1T + 1048576;

  const long T4 = 3276800;

  // zero the output accumulator (graph-capturable async memset)
  hipMemsetAsync(out, 0, (size_t)BSD * sizeof(float), stream);

  // fused: local_agg+gather+LN1 (256) | weight cast (768) | gating (800)
  front_kernel<<<1824, 256, 0, stream>>>(
      items, adj, emb, agg_a, alias, hbuf, xb, ln1g, ln1b,
      ids, Wg, Wn, eps, gates,
      Wq, Wk, Wv, Wo, W1, W2, wqkvT, woT, w1T, w2T);
  // fused QKV projection -> qkvb (128x128 tiles)
  bgemm3<<<dim3(6, 25, 4), 256, 0, stream>>>(xb, wqkvT, BSD, 196608, 768, 256,
      qkvb, 2457600, 0);
  attn_kernel<<<K_ * B_ * H_, 256, 0, stream>>>(qkvb, xb);  // o -> xb
  // O projection + residual + LN2 -> hbuf fp32 (h), xb bf16 (y)
  bgemm_oln<<<dim3(50, 1, 4), 256, 0, stream>>>(xb, woT, hbuf, xb, ln2g, ln2b);
  // FFN1: gelu(y@W1) -> tb bf16 (128x128 tiles)
  bgemm3<<<dim3(8, 25, 4), 256, 0, stream>>>(xb, w1T, BSD, 262144, 1024, 256,
      tb, T4, 1);
  // FFN2 + residual + gated combine -> out (atomic, z-parallel)
  bgemm_f2a<<<dim3(4, 50, 4), 256, 0, stream>>>(tb, w2T, hbuf, gates, out);
}

// Round 5
// 398.041 us; speedup vs baseline: 1.0791x; 1.0791x over previous
//
#include <hip/hip_runtime.h>
#include <hip/hip_bf16.h>
#include <math.h>

#define K_ 4
#define B_ 64
#define S_ 50
#define D_ 256
#define V_ 40000
#define H_ 4
#define DH_ 64
#define NEG_ (-1e9f)
#define SCALE_ 0.125f

typedef __attribute__((ext_vector_type(8))) __bf16 bf16x8v;
typedef __attribute__((ext_vector_type(4))) float f32x4v;

// ---------- helpers ----------
__device__ __forceinline__ float wred_sum(float v) {
#pragma unroll
  for (int off = 32; off > 0; off >>= 1) v += __shfl_xor(v, off, 64);
  return v;
}
__device__ __forceinline__ float wred_max(float v) {
#pragma unroll
  for (int off = 32; off > 0; off >>= 1) v = fmaxf(v, __shfl_xor(v, off, 64));
  return v;
}
__device__ __forceinline__ float softplusf(float x) {
  return (x > 20.f) ? x : log1pf(expf(x));
}
__device__ __forceinline__ float geluf(float x) {
  const float c = 0.7978845608028654f;  // sqrt(2/pi)
  float x3 = x * x * x;
  return 0.5f * x * (1.f + tanhf(c * (x + 0.044715f * x3)));
}
__device__ __forceinline__ float bf2f(unsigned int u) {
  return __uint_as_float(u << 16);
}
__device__ __forceinline__ unsigned short f2bf(float f) {
  unsigned u = __float_as_uint(f);
  return (unsigned short)((u + 0x7fffu + ((u >> 16) & 1u)) >> 16);
}
__device__ __forceinline__ bf16x8v cvt8(float4 a, float4 b) {
  bf16x8v r;
  r[0] = (__bf16)a.x; r[1] = (__bf16)a.y; r[2] = (__bf16)a.z; r[3] = (__bf16)a.w;
  r[4] = (__bf16)b.x; r[5] = (__bf16)b.y; r[6] = (__bf16)b.z; r[7] = (__bf16)b.w;
  return r;
}

// ---------- fused front: local_agg+gather+LN1 [0,256) | weight cast [256,1024)
// | gating [1024,1824). All three mutually independent.
__global__ __launch_bounds__(256) void front_kernel(
    const int* __restrict__ items, const int* __restrict__ adj,
    const float* __restrict__ emb, const float* __restrict__ agg_a,
    const int* __restrict__ alias_, float* __restrict__ hbuf,
    unsigned short* __restrict__ xb,
    const float* __restrict__ ln1g, const float* __restrict__ ln1b,
    const int* __restrict__ ids, const float* __restrict__ Wg,
    const float* __restrict__ Wn, const float* __restrict__ eps,
    float* __restrict__ gates,
    const float* __restrict__ wq, const float* __restrict__ wk,
    const float* __restrict__ wv, const float* __restrict__ wo,
    const float* __restrict__ w1, const float* __restrict__ w2,
    unsigned short* __restrict__ wqkvT, unsigned short* __restrict__ woT,
    unsigned short* __restrict__ w1T, unsigned short* __restrict__ w2T) {
  __shared__ __align__(16) char smem[62816];
  int bid = blockIdx.x;
  int t = threadIdx.x;

  if (bid < 256) {
    // ======== local aggregator (MFMA) + alias gather + LN1 ========
    typedef __bf16 (*arr264)[264];
    arr264 hgb = (arr264)smem;
    float (*e_f)[68] = (float(*)[68])(smem + 33792);
    unsigned char (*adj_s)[64] = (unsigned char(*)[64])(smem + 47392);
    arr264 a_sb = (arr264)(smem + 51488);
    __bf16 (*alp)[72] = (__bf16(*)[72])(smem + 53600);
    float* hl = (float*)smem;  // [50][260] overlay, used after PV

    int kb = bid;
    int k = kb >> 6, b = kb & 63;
    for (int c = t; c < 2048; c += 256) {
      int row = c >> 5, c8 = (c & 31) * 8;
      bf16x8v val;
      if (row < S_) {
        int g = items[kb * S_ + row];
        const float* src = emb + ((long)k * V_ + g) * D_ + c8;
        val = cvt8(*(const float4*)src, *(const float4*)(src + 4));
      } else {
#pragma unroll
        for (int e = 0; e < 8; ++e) val[e] = (__bf16)0.f;
      }
      *(bf16x8v*)&hgb[row][c8] = val;
    }
    if (t < 128) {
      int row = t >> 5, c8 = (t & 31) * 8;
      const float* src = agg_a + ((long)k * 4 + row) * D_ + c8;
      *(bf16x8v*)&a_sb[row][c8] = cvt8(*(const float4*)src, *(const float4*)(src + 4));
    }
    for (int c = t; c < 4096; c += 256) {
      int i = c >> 6, j = c & 63;
      adj_s[i][j] = (i < S_ && j < S_)
                        ? (unsigned char)adj[((long)b * S_ + i) * S_ + j] : 0;
    }
    __syncthreads();
    int w = t >> 6, lane = t & 63;
    int m16 = lane & 15, quad = lane >> 4;
    float e_sel[4][4];
#pragma unroll
    for (int nt = 0; nt < 4; ++nt)
#pragma unroll
      for (int rg = 0; rg < 4; ++rg) e_sel[nt][rg] = NEG_;
#pragma unroll
    for (int r = 0; r < 4; ++r) {
      f32x4v acc[4];
#pragma unroll
      for (int nt = 0; nt < 4; ++nt) acc[nt] = (f32x4v){0.f, 0.f, 0.f, 0.f};
#pragma unroll
      for (int k0 = 0; k0 < 8; ++k0) {
        int kc = k0 * 32 + quad * 8;
        bf16x8v hr = *(const bf16x8v*)&hgb[w * 16 + m16][kc];
        bf16x8v ar = *(const bf16x8v*)&a_sb[r][kc];
        bf16x8v af;
#pragma unroll
        for (int e = 0; e < 8; ++e) af[e] = (__bf16)((float)hr[e] * (float)ar[e]);
#pragma unroll
        for (int nt = 0; nt < 4; ++nt) {
          bf16x8v bf = *(const bf16x8v*)&hgb[nt * 16 + m16][kc];
          acc[nt] = __builtin_amdgcn_mfma_f32_16x16x32_bf16(af, bf, acc[nt], 0, 0, 0);
        }
      }
#pragma unroll
      for (int nt = 0; nt < 4; ++nt)
#pragma unroll
        for (int rg = 0; rg < 4; ++rg) {
          int i = w * 16 + quad * 4 + rg, j = nt * 16 + m16;
          if (adj_s[i][j] == r + 1) {
            float v = acc[nt][rg];
            e_sel[nt][rg] = (v >= 0.f) ? v : 0.2f * v;
          }
        }
    }
#pragma unroll
    for (int nt = 0; nt < 4; ++nt)
#pragma unroll
      for (int rg = 0; rg < 4; ++rg) {
        int i = w * 16 + quad * 4 + rg;
        if (i < S_) e_f[i][nt * 16 + m16] = e_sel[nt][rg];
      }
    __syncthreads();
    for (int i = w; i < S_; i += 4) {
      float val = (lane < S_) ? e_f[i][lane] : -INFINITY;
      float m = wred_max(val);
      float p = expf(val - m);
      float ssum = wred_sum(p);
      alp[i][lane] = (__bf16)(p / ssum);
    }
    __syncthreads();
    // PV with register-buffered accumulators (hgb/alp stay live)
    f32x4v acc16[16];
#pragma unroll
    for (int nt = 0; nt < 16; ++nt) {
      f32x4v acc = (f32x4v){0.f, 0.f, 0.f, 0.f};
#pragma unroll
      for (int k0 = 0; k0 < 2; ++k0) {
        int jb = k0 * 32 + quad * 8;
        bf16x8v af = *(const bf16x8v*)&alp[w * 16 + m16][jb];
        bf16x8v bf;
#pragma unroll
        for (int tt = 0; tt < 8; ++tt) bf[tt] = hgb[jb + tt][nt * 16 + m16];
        acc = __builtin_amdgcn_mfma_f32_16x16x32_bf16(af, bf, acc, 0, 0, 0);
      }
      acc16[nt] = acc;
    }
    __syncthreads();  // all hgb/alp reads done; overlay hl on smem
#pragma unroll
    for (int nt = 0; nt < 16; ++nt)
#pragma unroll
      for (int rg = 0; rg < 4; ++rg) {
        int i = w * 16 + quad * 4 + rg;
        if (i < S_) hl[i * 260 + nt * 16 + m16] = acc16[nt][rg];
      }
    __syncthreads();
    // alias gather + LN1 from LDS -> hbuf fp32 + xb bf16
    for (int s = w; s < S_; s += 4) {
      int src = alias_[b * S_ + s];
      const float4 v = *(const float4*)&hl[src * 260 + lane * 4];
      long off = ((long)kb * S_ + s) * D_ + lane * 4;
      *(float4*)(hbuf + off) = v;
      float sum = wred_sum(v.x + v.y + v.z + v.w);
      float sq = wred_sum(v.x * v.x + v.y * v.y + v.z * v.z + v.w * v.w);
      float mean = sum * (1.f / D_);
      float var = sq * (1.f / D_) - mean * mean;
      float rs = rsqrtf(var + 1e-5f);
      const float4 gv = *(const float4*)(ln1g + k * D_ + lane * 4);
      const float4 bv = *(const float4*)(ln1b + k * D_ + lane * 4);
      ushort4 o;
      o.x = f2bf((v.x - mean) * rs * gv.x + bv.x);
      o.y = f2bf((v.y - mean) * rs * gv.y + bv.y);
      o.z = f2bf((v.z - mean) * rs * gv.z + bv.z);
      o.w = f2bf((v.w - mean) * rs * gv.w + bv.w);
      *(ushort4*)(xb + off) = o;
    }
    return;
  }

  if (bid < 1024) {
    // ======== weight cast: LDS-tiled 64x64 transpose, coalesced both sides ====
    int tid = bid - 256;
    typedef unsigned short row66[66];
    row66* tile = (row66*)smem;  // needs 8448 B
    const float* src; unsigned short* dst; int C, R; int r0, c0;
    if (tid < 192) {  // Wq|Wk|Wv [256][256] per k -> wqkvT rows sect*256+
      int sect = tid >> 6; int rem = tid & 63;
      int k = rem >> 4, t2 = rem & 15;
      r0 = (t2 >> 2) * 64; c0 = (t2 & 3) * 64;
      src = ((sect == 0) ? wq : (sect == 1) ? wk : wv) + (long)k * 65536;
      dst = wqkvT + ((long)k * 768 + sect * 256) * 256;
      R = 256; C = 256;
    } else if (tid < 256) {  // Wo
      int rem = tid - 192; int k = rem >> 4, t2 = rem & 15;
      r0 = (t2 >> 2) * 64; c0 = (t2 & 3) * 64;
      src = wo + (long)k * 65536; dst = woT + (long)k * 65536;
      R = 256; C = 256;
    } else if (tid < 512) {  // W1 [256][1024] -> w1T [1024][256]
      int rem = tid - 256; int k = rem >> 6, t2 = rem & 63;
      r0 = (t2 >> 4) * 64; c0 = (t2 & 15) * 64;
      src = w1 + (long)k * 262144; dst = w1T + (long)k * 262144;
      R = 256; C = 1024;
    } else {  // W2 [1024][256] -> w2T [256][1024]
      int rem = tid - 512; int k = rem >> 6, t2 = rem & 63;
      r0 = (t2 >> 2) * 64; c0 = (t2 & 3) * 64;
      src = w2 + (long)k * 262144; dst = w2T + (long)k * 262144;
      R = 1024; C = 256;
    }
    int sr = t >> 2, sc = (t & 3) * 16;
    const float* p = src + (long)(r0 + sr) * C + c0 + sc;
#pragma unroll
    for (int q = 0; q < 4; ++q) {
      float4 f = *(const float4*)(p + q * 4);
      tile[sr][sc + q * 4 + 0] = f2bf(f.x);
      tile[sr][sc + q * 4 + 1] = f2bf(f.y);
      tile[sr][sc + q * 4 + 2] = f2bf(f.z);
      tile[sr][sc + q * 4 + 3] = f2bf(f.w);
    }
    __syncthreads();
    int dc = t >> 2, ch = (t & 3) * 16;  // dst row c0+dc, cols r0+ch..+16
    unsigned int wds[8];
#pragma unroll
    for (int i = 0; i < 8; ++i)
      wds[i] = (unsigned int)tile[ch + 2 * i][dc] |
               ((unsigned int)tile[ch + 2 * i + 1][dc] << 16);
    unsigned short* dp = dst + (long)(c0 + dc) * R + r0 + ch;
    uint4 o0 = make_uint4(wds[0], wds[1], wds[2], wds[3]);
    uint4 o1 = make_uint4(wds[4], wds[5], wds[6], wds[7]);
    *(uint4*)dp = o0;
    *(uint4*)(dp + 8) = o1;
    return;
  }

  {
    // ======== noisy top-k gating ========
    int w = t >> 6, lane = t & 63;
    int item = (bid - 1024) * 4 + w;  // b*S+s
    int b = item / S_, s = item % S_;
    int d0 = lane * 4;
    float4 hs = make_float4(0.f, 0.f, 0.f, 0.f);
#pragma unroll
    for (int k = 0; k < K_; ++k) {
      int id = ids[(k * B_ + b) * S_ + s];
      const float4 e = *(const float4*)(emb + ((long)k * V_ + id) * D_ + d0);
      hs.x += e.x; hs.y += e.y; hs.z += e.z; hs.w += e.w;
    }
    hs.x *= 0.25f; hs.y *= 0.25f; hs.z *= 0.25f; hs.w *= 0.25f;
    float logit[4];
#pragma unroll
    for (int j = 0; j < K_; ++j) {
      float pg = hs.x * Wg[(d0 + 0) * K_ + j] + hs.y * Wg[(d0 + 1) * K_ + j] +
                 hs.z * Wg[(d0 + 2) * K_ + j] + hs.w * Wg[(d0 + 3) * K_ + j];
      float pn = hs.x * Wn[(d0 + 0) * K_ + j] + hs.y * Wn[(d0 + 1) * K_ + j] +
                 hs.z * Wn[(d0 + 2) * K_ + j] + hs.w * Wn[(d0 + 3) * K_ + j];
      pg = wred_sum(pg);
      pn = wred_sum(pn);
      logit[j] = pg + softplusf(pn) * eps[item * K_ + j];
    }
    if (lane == 0) {
      int i0 = 0; float v0 = logit[0];
      for (int j = 1; j < K_; ++j) if (logit[j] > v0) { v0 = logit[j]; i0 = j; }
      int i1 = -1; float v1 = 0.f;
      for (int j = 0; j < K_; ++j)
        if (j != i0 && (i1 < 0 || logit[j] > v1)) { v1 = logit[j]; i1 = j; }
      float w0 = 1.f / (1.f + expf(v1 - v0));
      float w1 = 1.f - w0;
#pragma unroll
      for (int j = 0; j < K_; ++j)
        gates[item * K_ + j] = (j == i0) ? w0 : ((j == i1) ? w1 : 0.f);
    }
  }
}

// ---------- bf16 MFMA GEMM: 128x128 tile, 4 waves (2x2), BK=64, Bt=[N][Kd].
__global__ __launch_bounds__(256) void bgemm3(
    const unsigned short* __restrict__ A, const unsigned short* __restrict__ Bt,
    long strideA, long strideBt, int N, int Kd,
    unsigned short* __restrict__ Cb, long strideCb, int act) {
  __shared__ unsigned short sA[128][72];
  __shared__ unsigned short sB[128][72];
  int z = blockIdx.z;
  A += (long)z * strideA;
  Bt += (long)z * strideBt;
  int t = threadIdx.x, w = t >> 6, lane = t & 63;
  int wr = w >> 1, wc = w & 1;
  int row0 = blockIdx.y * 128, col0 = blockIdx.x * 128;
  int m16 = lane & 15, quad = lane >> 4;
  f32x4v acc[4][4];
#pragma unroll
  for (int mr = 0; mr < 4; ++mr)
#pragma unroll
    for (int nr = 0; nr < 4; ++nr) acc[mr][nr] = (f32x4v){0.f, 0.f, 0.f, 0.f};
  int sr = t >> 1, sc = (t & 1) * 32;
  const unsigned short* pa = A + (long)(row0 + sr) * Kd + sc;
  const unsigned short* pb = Bt + (long)(col0 + sr) * Kd + sc;
  uint4 a0 = *(const uint4*)(pa);
  uint4 a1 = *(const uint4*)(pa + 8);
  uint4 a2 = *(const uint4*)(pa + 16);
  uint4 a3 = *(const uint4*)(pa + 24);
  uint4 b0 = *(const uint4*)(pb);
  uint4 b1 = *(const uint4*)(pb + 8);
  uint4 b2 = *(const uint4*)(pb + 16);
  uint4 b3 = *(const uint4*)(pb + 24);
  for (int k0 = 0; k0 < Kd; k0 += 64) {
    __syncthreads();
    *(uint4*)&sA[sr][sc] = a0;
    *(uint4*)&sA[sr][sc + 8] = a1;
    *(uint4*)&sA[sr][sc + 16] = a2;
    *(uint4*)&sA[sr][sc + 24] = a3;
    *(uint4*)&sB[sr][sc] = b0;
    *(uint4*)&sB[sr][sc + 8] = b1;
    *(uint4*)&sB[sr][sc + 16] = b2;
    *(uint4*)&sB[sr][sc + 24] = b3;
    if (k0 + 64 < Kd) {
      a0 = *(const uint4*)(pa + k0 + 64);
      a1 = *(const uint4*)(pa + k0 + 72);
      a2 = *(const uint4*)(pa + k0 + 80);
      a3 = *(const uint4*)(pa + k0 + 88);
      b0 = *(const uint4*)(pb + k0 + 64);
      b1 = *(const uint4*)(pb + k0 + 72);
      b2 = *(const uint4*)(pb + k0 + 80);
      b3 = *(const uint4*)(pb + k0 + 88);
    }
    __syncthreads();
#pragma unroll
    for (int half = 0; half < 2; ++half) {
      int kg = half * 32 + quad * 8;
      bf16x8v af[4], bf[4];
#pragma unroll
      for (int i = 0; i < 4; ++i) {
        af[i] = *(const bf16x8v*)&sA[wr * 64 + i * 16 + m16][kg];
        bf[i] = *(const bf16x8v*)&sB[wc * 64 + i * 16 + m16][kg];
      }
#pragma unroll
      for (int mr = 0; mr < 4; ++mr)
#pragma unroll
        for (int nr = 0; nr < 4; ++nr)
          acc[mr][nr] = __builtin_amdgcn_mfma_f32_16x16x32_bf16(
              af[mr], bf[nr], acc[mr][nr], 0, 0, 0);
    }
  }
#pragma unroll
  for (int mr = 0; mr < 4; ++mr) {
    int rbase = row0 + wr * 64 + mr * 16 + quad * 4;
#pragma unroll
    for (int nr = 0; nr < 4; ++nr) {
      int col = col0 + wc * 64 + nr * 16 + m16;
#pragma unroll
      for (int i2 = 0; i2 < 4; ++i2) {
        float vv = acc[mr][nr][i2];
        if (act == 1) vv = geluf(vv);
        Cb[(long)z * strideCb + (long)(rbase + i2) * N + col] = f2bf(vv);
      }
    }
  }
}

// ---------- causal MHA via MFMA (local_agg pattern); P in bf16 hi+lo ----------
// block = (k*B+b)*H + h; 4 waves, wave w owns row-tile w (rows 16w..16w+15)
__global__ __launch_bounds__(256) void attn_mfma(
    const unsigned short* __restrict__ qkv, unsigned short* __restrict__ o) {
  __shared__ __bf16 qs[64][72], ks[64][72], vs[64][72];
  __shared__ __bf16 psh[64][72], psl[64][72];
  int idx = blockIdx.x;
  int h = idx & 3;
  int kb = idx >> 2;
  long base = (long)kb * S_ * 768 + h * DH_;
  int t = threadIdx.x;
  // load Q,K,V rows (bf16 direct); zero pad rows 50..63
  for (int f = t; f < 512; f += 256) {
    int row = f >> 3, c8 = (f & 7) * 8;
    uint4 zq = make_uint4(0, 0, 0, 0), zk = zq, zv = zq;
    if (row < S_) {
      long g = base + (long)row * 768 + c8;
      zq = *(const uint4*)(qkv + g);
      zk = *(const uint4*)(qkv + g + 256);
      zv = *(const uint4*)(qkv + g + 512);
    }
    *(uint4*)&qs[row][c8] = zq;
    *(uint4*)&ks[row][c8] = zk;
    *(uint4*)&vs[row][c8] = zv;
  }
  __syncthreads();
  int w = t >> 6, lane = t & 63;
  int m16 = lane & 15, quad = lane >> 4;
  // ---- QK^T: S[i][j], i = w*16 + quad*4 + rg, j = nt*16 + m16, K=64
  f32x4v sacc[4];
#pragma unroll
  for (int nt = 0; nt < 4; ++nt) sacc[nt] = (f32x4v){0.f, 0.f, 0.f, 0.f};
#pragma unroll
  for (int k0 = 0; k0 < 2; ++k0) {
    int kc = k0 * 32 + quad * 8;
    bf16x8v af = *(const bf16x8v*)&qs[w * 16 + m16][kc];
#pragma unroll
    for (int nt = 0; nt < 4; ++nt) {
      bf16x8v bf = *(const bf16x8v*)&ks[nt * 16 + m16][kc];
      sacc[nt] = __builtin_amdgcn_mfma_f32_16x16x32_bf16(af, bf, sacc[nt], 0, 0, 0);
    }
  }
  // ---- masked softmax per row; row's cols live in 4 regs x 16 m16-lanes
  // (16-lane shfl_xor offsets 1,2,4,8 stay inside the quad owning the row)
#pragma unroll
  for (int rg = 0; rg < 4; ++rg) {
    int i = w * 16 + quad * 4 + rg;
    float v4[4];
    if (i < S_) {
      float mx = -INFINITY;
#pragma unroll
      for (int nt = 0; nt < 4; ++nt) {
        int j = nt * 16 + m16;
        float vv = (j <= i) ? sacc[nt][rg] * SCALE_ : -INFINITY;
        v4[nt] = vv;
        mx = fmaxf(mx, vv);
      }
#pragma unroll
      for (int off = 1; off < 16; off <<= 1)
        mx = fmaxf(mx, __shfl_xor(mx, off, 64));
      float sum = 0.f;
#pragma unroll
      for (int nt = 0; nt < 4; ++nt) {
        v4[nt] = expf(v4[nt] - mx);
        sum += v4[nt];
      }
#pragma unroll
      for (int off = 1; off < 16; off <<= 1) sum += __shfl_xor(sum, off, 64);
      float inv = 1.f / sum;
#pragma unroll
      for (int nt = 0; nt < 4; ++nt) v4[nt] *= inv;
    } else {
#pragma unroll
      for (int nt = 0; nt < 4; ++nt) v4[nt] = 0.f;
    }
    // split into bf16 hi + lo for full-precision PV
#pragma unroll
    for (int nt = 0; nt < 4; ++nt) {
      __bf16 hi = (__bf16)v4[nt];
      psh[i][nt * 16 + m16] = hi;
      psl[i][nt * 16 + m16] = (__bf16)(v4[nt] - (float)hi);
    }
  }
  __syncthreads();
  // ---- PV: O[i][d] = sum_j P[i][j] V[j][d]; B-fragment via scalar V reads
  f32x4v oacc[4];
#pragma unroll
  for (int nt = 0; nt < 4; ++nt) oacc[nt] = (f32x4v){0.f, 0.f, 0.f, 0.f};
#pragma unroll
  for (int k0 = 0; k0 < 2; ++k0) {
    int jb = k0 * 32 + quad * 8;
    bf16x8v ah = *(const bf16x8v*)&psh[w * 16 + m16][jb];
    bf16x8v al = *(const bf16x8v*)&psl[w * 16 + m16][jb];
#pragma unroll
    for (int nt = 0; nt < 4; ++nt) {
      bf16x8v bf;
#pragma unroll
      for (int tt = 0; tt < 8; ++tt) bf[tt] = vs[jb + tt][nt * 16 + m16];
      oacc[nt] = __builtin_amdgcn_mfma_f32_16x16x32_bf16(ah, bf, oacc[nt], 0, 0, 0);
      oacc[nt] = __builtin_amdgcn_mfma_f32_16x16x32_bf16(al, bf, oacc[nt], 0, 0, 0);
    }
  }
#pragma unroll
  for (int nt = 0; nt < 4; ++nt)
#pragma unroll
    for (int rg = 0; rg < 4; ++rg) {
      int i = w * 16 + quad * 4 + rg;
      if (i < S_)
        o[((long)kb * S_ + i) * D_ + h * DH_ + nt * 16 + m16] = f2bf(oacc[nt][rg]);
    }
}

// ---------- O-projection + residual + LN2 fused (64x256 tile, full rows) ------
__global__ __launch_bounds__(256) void bgemm_oln(
    const unsigned short* __restrict__ A, const unsigned short* __restrict__ Bt,
    float* __restrict__ hbuf, unsigned short* __restrict__ y,
    const float* __restrict__ g2, const float* __restrict__ b2) {
  __shared__ unsigned short sA[64][72];
  __shared__ unsigned short sB[256][72];
  const long BSD = (long)B_ * S_ * D_;
  int z = blockIdx.z;
  const unsigned short* Ap = A + (long)z * BSD;
  const unsigned short* Bp = Bt + (long)z * 65536;
  int t = threadIdx.x, w = t >> 6, lane = t & 63;
  int row0 = blockIdx.x * 64;
  int m16 = lane & 15, quad = lane >> 4;
  f32x4v acc[16];
#pragma unroll
  for (int nt = 0; nt < 16; ++nt) acc[nt] = (f32x4v){0.f, 0.f, 0.f, 0.f};
  int sr = t >> 2, sc = (t & 3) * 16;
  const unsigned short* pa = Ap + (long)(row0 + sr) * 256 + sc;
  const unsigned short* pb = Bp + (long)sr * 256 + sc;
  uint4 a0 = *(const uint4*)pa;
  uint4 a1 = *(const uint4*)(pa + 8);
  uint4 bv[8];
#pragma unroll
  for (int q = 0; q < 4; ++q) {
    bv[2 * q] = *(const uint4*)(pb + q * 16384);
    bv[2 * q + 1] = *(const uint4*)(pb + q * 16384 + 8);
  }
  for (int k0 = 0; k0 < 256; k0 += 64) {
    __syncthreads();
    *(uint4*)&sA[sr][sc] = a0;
    *(uint4*)&sA[sr][sc + 8] = a1;
#pragma unroll
    for (int q = 0; q < 4; ++q) {
      *(uint4*)&sB[q * 64 + sr][sc] = bv[2 * q];
      *(uint4*)&sB[q * 64 + sr][sc + 8] = bv[2 * q + 1];
    }
    if (k0 + 64 < 256) {
      a0 = *(const uint4*)(pa + k0 + 64);
      a1 = *(const uint4*)(pa + k0 + 72);
#pragma unroll
      for (int q = 0; q < 4; ++q) {
        bv[2 * q] = *(const uint4*)(pb + q * 16384 + k0 + 64);
        bv[2 * q + 1] = *(const uint4*)(pb + q * 16384 + k0 + 72);
      }
    }
    __syncthreads();
#pragma unroll
    for (int half = 0; half < 2; ++half) {
      int kg = half * 32 + quad * 8;
      bf16x8v af = *(const bf16x8v*)&sA[w * 16 + m16][kg];
#pragma unroll
      for (int nt = 0; nt < 16; ++nt) {
        bf16x8v bf = *(const bf16x8v*)&sB[nt * 16 + m16][kg];
        acc[nt] = __builtin_amdgcn_mfma_f32_16x16x32_bf16(af, bf, acc[nt], 0, 0, 0);
      }
    }
  }
  long zoff = (long)z * BSD;
  int rbase = row0 + w * 16 + quad * 4;
#pragma unroll
  for (int nt = 0; nt < 16; ++nt)
#pragma unroll
    for (int i2 = 0; i2 < 4; ++i2) {
      long off = zoff + (long)(rbase + i2) * 256 + nt * 16 + m16;
      float vv = acc[nt][i2] + hbuf[off];
      acc[nt][i2] = vv;
      hbuf[off] = vv;
    }
  float mean[4], rstd[4];
#pragma unroll
  for (int i2 = 0; i2 < 4; ++i2) {
    float s = 0.f, q = 0.f;
#pragma unroll
    for (int nt = 0; nt < 16; ++nt) {
      float vv = acc[nt][i2];
      s += vv; q += vv * vv;
    }
#pragma unroll
    for (int off = 1; off < 16; off <<= 1) {
      s += __shfl_xor(s, off, 64);
      q += __shfl_xor(q, off, 64);
    }
    float m = s * (1.f / D_);
    float var = q * (1.f / D_) - m * m;
    mean[i2] = m;
    rstd[i2] = rsqrtf(var + 1e-5f);
  }
#pragma unroll
  for (int nt = 0; nt < 16; ++nt) {
    float gv = g2[z * D_ + nt * 16 + m16];
    float bvv = b2[z * D_ + nt * 16 + m16];
#pragma unroll
    for (int i2 = 0; i2 < 4; ++i2) {
      long off = zoff + (long)(rbase + i2) * 256 + nt * 16 + m16;
      y[off] = f2bf((acc[nt][i2] - mean[i2]) * rstd[i2] * gv + bvv);
    }
  }
}

// ---------- FFN2 + residual + gated combine, z in grid, atomic accumulate ----
__global__ __launch_bounds__(256) void bgemm_f2a(
    const unsigned short* __restrict__ A, const unsigned short* __restrict__ Bt,
    const float* __restrict__ hbuf, const float* __restrict__ gates,
    float* __restrict__ out) {
  __shared__ unsigned short sA[64][72];
  __shared__ unsigned short sB[64][72];
  const long T4 = 3276800;
  const long BSD = (long)B_ * S_ * D_;
  int z = blockIdx.z;
  int t = threadIdx.x, w = t >> 6, lane = t & 63;
  int col0 = blockIdx.x * 64, row0 = blockIdx.y * 64;
  int m16 = lane & 15, quad = lane >> 4;
  f32x4v acc[4];
#pragma unroll
  for (int nt = 0; nt < 4; ++nt) acc[nt] = (f32x4v){0.f, 0.f, 0.f, 0.f};
  int sr = t >> 2, sc = (t & 3) * 16;
  const unsigned short* pa = A + (long)z * T4 + (long)(row0 + sr) * 1024 + sc;
  const unsigned short* pb = Bt + (long)z * 262144 + (long)(col0 + sr) * 1024 + sc;
  uint4 a0 = *(const uint4*)pa;
  uint4 a1 = *(const uint4*)(pa + 8);
  uint4 b0 = *(const uint4*)pb;
  uint4 b1 = *(const uint4*)(pb + 8);
  for (int k0 = 0; k0 < 1024; k0 += 64) {
    __syncthreads();
    *(uint4*)&sA[sr][sc] = a0;
    *(uint4*)&sA[sr][sc + 8] = a1;
    *(uint4*)&sB[sr][sc] = b0;
    *(uint4*)&sB[sr][sc + 8] = b1;
    if (k0 + 64 < 1024) {
      a0 = *(const uint4*)(pa + k0 + 64);
      a1 = *(const uint4*)(pa + k0 + 72);
      b0 = *(const uint4*)(pb + k0 + 64);
      b1 = *(const uint4*)(pb + k0 + 72);
    }
    __syncthreads();
#pragma unroll
    for (int half = 0; half < 2; ++half) {
      int kg = half * 32 + quad * 8;
      bf16x8v af = *(const bf16x8v*)&sA[w * 16 + m16][kg];
#pragma unroll
      for (int nt = 0; nt < 4; ++nt) {
        bf16x8v bf = *(const bf16x8v*)&sB[nt * 16 + m16][kg];
        acc[nt] = __builtin_amdgcn_mfma_f32_16x16x32_bf16(af, bf, acc[nt], 0, 0, 0);
      }
    }
  }
  int rbase = row0 + w * 16 + quad * 4;
#pragma unroll
  for (int i2 = 0; i2 < 4; ++i2) {
    float gz = gates[(rbase + i2) * 4 + z];
    if (gz != 0.f) {
#pragma unroll
      for (int nt = 0; nt < 4; ++nt) {
        long off = (long)(rbase + i2) * 256 + col0 + nt * 16 + m16;
        float vv = gz * (acc[nt][i2] + hbuf[(long)z * BSD + off]);
        atomicAdd(&out[off], vv);
      }
    }
  }
}

extern "C" void kernel_launch(void* const* d_in, const int* in_sizes, int n_in,
                              void* d_out, int out_size, void* d_ws,
                              size_t ws_size, hipStream_t stream) {
  const int* ids = (const int*)d_in[0];
  const int* items = (const int*)d_in[1];
  const int* adj = (const int*)d_in[2];
  const int* alias = (const int*)d_in[3];
  const float* eps = (const float*)d_in[4];
  const float* emb = (const float*)d_in[5];
  const float* agg_a = (const float*)d_in[6];
  const float* Wq = (const float*)d_in[7];
  const float* Wk = (const float*)d_in[8];
  const float* Wv = (const float*)d_in[9];
  const float* Wo = (const float*)d_in[10];
  const float* ln1g = (const float*)d_in[11];
  const float* ln1b = (const float*)d_in[12];
  const float* W1 = (const float*)d_in[13];
  const float* W2 = (const float*)d_in[14];
  const float* ln2g = (const float*)d_in[15];
  const float* ln2b = (const float*)d_in[16];
  const float* Wg = (const float*)d_in[17];
  const float* Wn = (const float*)d_in[18];
  float* out = (float*)d_out;

  const long BSD = (long)B_ * S_ * D_;  // 819200
  float* ws = (float*)d_ws;
  float* gates = ws;                    // 16384 fp32
  float* hbuf = ws + 16384;             // [K,B,S,D] fp32 residual stream
  unsigned short* ub = (unsigned short*)(ws + 16384 + 4 * BSD);
  unsigned short* xb = ub;              // x / attn-o / y slot [K,B,S,D] bf16
  unsigned short* qkvb = ub + 3276800;  // [K,B*S,768]
  unsigned short* tb = qkvb;            // FFN hidden [K,B*S,1024]
  unsigned short* wqkvT = ub + 16384000;
  unsigned short* woT = wqkvT + 786432;
  unsigned short* w1T = woT + 262144;
  unsigned short* w2T = w1T + 1048576;

  const long T4 = 3276800;

  hipMemsetAsync(out, 0, (size_t)BSD * sizeof(float), stream);

  // fused: local_agg+gather+LN1 (256) | weight cast (768) | gating (800)
  front_kernel<<<1824, 256, 0, stream>>>(
      items, adj, emb, agg_a, alias, hbuf, xb, ln1g, ln1b,
      ids, Wg, Wn, eps, gates,
      Wq, Wk, Wv, Wo, W1, W2, wqkvT, woT, w1T, w2T);
  // fused QKV projection -> qkvb (128x128 tiles)
  bgemm3<<<dim3(6, 25, 4), 256, 0, stream>>>(xb, wqkvT, BSD, 196608, 768, 256,
      qkvb, 2457600, 0);
  attn_mfma<<<K_ * B_ * H_, 256, 0, stream>>>(qkvb, xb);  // o -> xb
  // O projection + residual + LN2 -> hbuf fp32 (h), xb bf16 (y)
  bgemm_oln<<<dim3(50, 1, 4), 256, 0, stream>>>(xb, woT, hbuf, xb, ln2g, ln2b);
  // FFN1: gelu(y@W1) -> tb bf16 (128x128 tiles)
  bgemm3<<<dim3(8, 25, 4), 256, 0, stream>>>(xb, w1T, BSD, 262144, 1024, 256,
      tb, T4, 1);
  // FFN2 + residual + gated combine -> out (atomic, z-parallel)
  bgemm_f2a<<<dim3(4, 50, 4), 256, 0, stream>>>(tb, w2T, hbuf, gates, out);
}